// Round 5
// baseline (51.938 us; speedup 1.0000x reference)
//
#include <hip/hip_runtime.h>
#include <math.h>

#define NSEG 4096
#define DD   128

typedef float f4 __attribute__((ext_vector_type(4)));

// first index n with seg[n] >= g (seg sorted ascending)
__device__ __forceinline__ int lower_bound(const int* __restrict__ seg, int N, int g) {
    int lo = 0, hi = N;
    while (lo < hi) {
        int mid = (lo + hi) >> 1;
        if (seg[mid] < g) lo = mid + 1; else hi = mid;
    }
    return lo;
}

// ---------------- single fused kernel: bounds + gate + online softmax + readout ----------------
// One 256-thread block per segment. 64-row tiles, 8 rows per thread
// (rows base+rg+8k, k=0..7), one barrier per tile, next tile prefetched
// before the barrier. feat read exactly once (non-temporal).
__global__ __launch_bounds__(256) void fused_kernel(
        const float* __restrict__ feat,
        const float* __restrict__ gw,
        const float* __restrict__ gb,
        const int*  __restrict__ seg,
        int N,
        float* __restrict__ out) {
    __shared__ float gs[2][64];     // double-buffered per-tile gates
    __shared__ f4    red[8][32];

    int g = blockIdx.x;
    int s = lower_bound(seg, N, g);         // uniform across block -> scalar loads
    int e = lower_bound(seg, N, g + 1);
    int len = e - s;

    int tid = threadIdx.x;
    int rg  = tid >> 5;     // row group 0..7
    int c   = tid & 31;     // float4 column

    const f4* fp = (const f4*)feat;
    f4    w4 = ((const f4*)gw)[c];
    float b0 = gb[0];

    float m = -INFINITY, l = 0.0f;
    f4 acc = {0.f, 0.f, 0.f, 0.f};

    int ntiles = (len + 63) >> 6;

    f4 cur0, cur1, cur2, cur3, cur4, cur5, cur6, cur7;
    f4 nxt0 = {0,0,0,0}, nxt1 = {0,0,0,0}, nxt2 = {0,0,0,0}, nxt3 = {0,0,0,0};
    f4 nxt4 = {0,0,0,0}, nxt5 = {0,0,0,0}, nxt6 = {0,0,0,0}, nxt7 = {0,0,0,0};

    // prefetch tile 0
    {
        int n0 = s + rg;
        if (n0      < e) nxt0 = __builtin_nontemporal_load(&fp[(n0     ) * 32 + c]);
        if (n0 + 8  < e) nxt1 = __builtin_nontemporal_load(&fp[(n0 + 8 ) * 32 + c]);
        if (n0 + 16 < e) nxt2 = __builtin_nontemporal_load(&fp[(n0 + 16) * 32 + c]);
        if (n0 + 24 < e) nxt3 = __builtin_nontemporal_load(&fp[(n0 + 24) * 32 + c]);
        if (n0 + 32 < e) nxt4 = __builtin_nontemporal_load(&fp[(n0 + 32) * 32 + c]);
        if (n0 + 40 < e) nxt5 = __builtin_nontemporal_load(&fp[(n0 + 40) * 32 + c]);
        if (n0 + 48 < e) nxt6 = __builtin_nontemporal_load(&fp[(n0 + 48) * 32 + c]);
        if (n0 + 56 < e) nxt7 = __builtin_nontemporal_load(&fp[(n0 + 56) * 32 + c]);
    }

    for (int t = 0; t < ntiles; ++t) {
        int base = s + t * 64;
        int n0 = base + rg;
        cur0 = nxt0; cur1 = nxt1; cur2 = nxt2; cur3 = nxt3;
        cur4 = nxt4; cur5 = nxt5; cur6 = nxt6; cur7 = nxt7;

        // prefetch next tile (issued before this tile's barrier)
        int p0 = n0 + 64;
        nxt0 = (f4){0,0,0,0}; nxt1 = (f4){0,0,0,0}; nxt2 = (f4){0,0,0,0}; nxt3 = (f4){0,0,0,0};
        nxt4 = (f4){0,0,0,0}; nxt5 = (f4){0,0,0,0}; nxt6 = (f4){0,0,0,0}; nxt7 = (f4){0,0,0,0};
        if (p0      < e) nxt0 = __builtin_nontemporal_load(&fp[(p0     ) * 32 + c]);
        if (p0 + 8  < e) nxt1 = __builtin_nontemporal_load(&fp[(p0 + 8 ) * 32 + c]);
        if (p0 + 16 < e) nxt2 = __builtin_nontemporal_load(&fp[(p0 + 16) * 32 + c]);
        if (p0 + 24 < e) nxt3 = __builtin_nontemporal_load(&fp[(p0 + 24) * 32 + c]);
        if (p0 + 32 < e) nxt4 = __builtin_nontemporal_load(&fp[(p0 + 32) * 32 + c]);
        if (p0 + 40 < e) nxt5 = __builtin_nontemporal_load(&fp[(p0 + 40) * 32 + c]);
        if (p0 + 48 < e) nxt6 = __builtin_nontemporal_load(&fp[(p0 + 48) * 32 + c]);
        if (p0 + 56 < e) nxt7 = __builtin_nontemporal_load(&fp[(p0 + 56) * 32 + c]);

        // gate dots for this thread's 8 rows; reduce across the 32-lane half
        float d0 = cur0.x*w4.x + cur0.y*w4.y + cur0.z*w4.z + cur0.w*w4.w;
        float d1 = cur1.x*w4.x + cur1.y*w4.y + cur1.z*w4.z + cur1.w*w4.w;
        float d2 = cur2.x*w4.x + cur2.y*w4.y + cur2.z*w4.z + cur2.w*w4.w;
        float d3 = cur3.x*w4.x + cur3.y*w4.y + cur3.z*w4.z + cur3.w*w4.w;
        float d4 = cur4.x*w4.x + cur4.y*w4.y + cur4.z*w4.z + cur4.w*w4.w;
        float d5 = cur5.x*w4.x + cur5.y*w4.y + cur5.z*w4.z + cur5.w*w4.w;
        float d6 = cur6.x*w4.x + cur6.y*w4.y + cur6.z*w4.z + cur6.w*w4.w;
        float d7 = cur7.x*w4.x + cur7.y*w4.y + cur7.z*w4.z + cur7.w*w4.w;
        #pragma unroll
        for (int off = 16; off; off >>= 1) {
            d0 += __shfl_xor(d0, off);
            d1 += __shfl_xor(d1, off);
            d2 += __shfl_xor(d2, off);
            d3 += __shfl_xor(d3, off);
            d4 += __shfl_xor(d4, off);
            d5 += __shfl_xor(d5, off);
            d6 += __shfl_xor(d6, off);
            d7 += __shfl_xor(d7, off);
        }
        int buf = t & 1;
        if (c == 0) {
            gs[buf][rg]      = (n0      < e) ? d0 + b0 : -INFINITY;
            gs[buf][rg + 8]  = (n0 + 8  < e) ? d1 + b0 : -INFINITY;
            gs[buf][rg + 16] = (n0 + 16 < e) ? d2 + b0 : -INFINITY;
            gs[buf][rg + 24] = (n0 + 24 < e) ? d3 + b0 : -INFINITY;
            gs[buf][rg + 32] = (n0 + 32 < e) ? d4 + b0 : -INFINITY;
            gs[buf][rg + 40] = (n0 + 40 < e) ? d5 + b0 : -INFINITY;
            gs[buf][rg + 48] = (n0 + 48 < e) ? d6 + b0 : -INFINITY;
            gs[buf][rg + 56] = (n0 + 56 < e) ? d7 + b0 : -INFINITY;
        }
        __syncthreads();
        // (gs[buf] is next rewritten at t+2, which is after barrier t+1 -> safe)

        // wave-parallel max & expsum over the 64 tile gates (full 64-lane butterfly)
        float gj = gs[buf][tid & 63];
        float tmax = gj;
        #pragma unroll
        for (int off = 32; off; off >>= 1) tmax = fmaxf(tmax, __shfl_xor(tmax, off));
        float m_new = fmaxf(m, tmax);           // finite: tile has >=1 valid row
        float scale = __expf(m - m_new);        // first tile: exp(-inf)=0; acc,l are 0
        float pj = __expf(gj - m_new);          // OOB rows: exp(-inf)=0
        float psum = pj;
        #pragma unroll
        for (int off = 32; off; off >>= 1) psum += __shfl_xor(psum, off);
        l = l * scale + psum;

        float p0w = __expf(gs[buf][rg]      - m_new);
        float p1w = __expf(gs[buf][rg + 8]  - m_new);
        float p2w = __expf(gs[buf][rg + 16] - m_new);
        float p3w = __expf(gs[buf][rg + 24] - m_new);
        float p4w = __expf(gs[buf][rg + 32] - m_new);
        float p5w = __expf(gs[buf][rg + 40] - m_new);
        float p6w = __expf(gs[buf][rg + 48] - m_new);
        float p7w = __expf(gs[buf][rg + 56] - m_new);
        acc = acc * scale
            + p0w * cur0 + p1w * cur1 + p2w * cur2 + p3w * cur3
            + p4w * cur4 + p5w * cur5 + p6w * cur6 + p7w * cur7;
        m = m_new;
    }

    // reduce the 8 row-group partial accumulators, normalize, write
    red[rg][c] = acc;
    __syncthreads();
    if (rg == 0) {
        f4 r = red[0][c];
        #pragma unroll
        for (int k = 1; k < 8; ++k) r += red[k][c];
        float invl = (len > 0) ? 1.0f / l : 0.0f;   // empty segment -> zeros
        r *= invl;
        ((f4*)out)[g * 32 + c] = r;
    }
}

// ---------------- launch ----------------
extern "C" void kernel_launch(void* const* d_in, const int* in_sizes, int n_in,
                              void* d_out, int out_size, void* d_ws, size_t ws_size,
                              hipStream_t stream) {
    const float* feat = (const float*)d_in[0];
    const float* gw   = (const float*)d_in[1];
    const float* gb   = (const float*)d_in[2];
    const int*   seg  = (const int*)d_in[3];
    int N = in_sizes[0] / DD;                        // 500000

    fused_kernel<<<NSEG, 256, 0, stream>>>(feat, gw, gb, seg, N, (float*)d_out);
}

// Round 7
// 46.531 us; speedup vs baseline: 1.1162x; 1.1162x over previous
//
#include <hip/hip_runtime.h>
#include <math.h>

#define NSEG 4096
#define DD   128
#define NEG  (-1e30f)

typedef float f4 __attribute__((ext_vector_type(4)));

// first index n with seg[n] >= g (seg sorted ascending)
__device__ __forceinline__ int lower_bound(const int* __restrict__ seg, int N, int g) {
    int lo = 0, hi = N;
    while (lo < hi) {
        int mid = (lo + hi) >> 1;
        if (seg[mid] < g) lo = mid + 1; else hi = mid;
    }
    return lo;
}

// ---------------- single fused kernel: bounds + gate + online softmax + readout ----------------
// One 256-thread block per segment. Each 32-lane row-group keeps a PRIVATE
// online-softmax state (m, l, acc); the 8 group states merge once at the end.
// Main loop has NO barriers and FULLY UNIFORM control flow: all loads are
// unconditional with row index clamped to e-1 (always in-bounds); row
// validity is per-lane selects only. Invalid rows carry gate NEG so their
// softmax weight exp(NEG - m) == 0 exactly; never-valid groups are cancelled
// at the merge by weight exp(NEG - M) == 0.
__global__ __launch_bounds__(256) void fused_kernel(
        const float* __restrict__ feat,
        const float* __restrict__ gw,
        const float* __restrict__ gb,
        const int*  __restrict__ seg,
        int N,
        float* __restrict__ out) {
    __shared__ f4    red[8][32];
    __shared__ float mred[8];
    __shared__ float lred[8];

    int g = blockIdx.x;
    int s = lower_bound(seg, N, g);         // uniform across block
    int e = lower_bound(seg, N, g + 1);
    int len = e - s;

    int tid = threadIdx.x;
    int rg  = tid >> 5;     // row group 0..7
    int c   = tid & 31;     // float4 column

    if (len <= 0) {                          // uniform per block -> legal early-out
        if (rg == 0) ((f4*)out)[g * 32 + c] = (f4){0.f, 0.f, 0.f, 0.f};
        return;
    }

    const f4* fp = (const f4*)feat;
    f4    w4 = ((const f4*)gw)[c];
    float b0 = gb[0];

    float m = NEG, l = 0.0f;
    f4 acc = {0.f, 0.f, 0.f, 0.f};

    int ntiles = (len + 31) >> 5;
    int emax = e - 1;                        // >= s since len > 0

    // prefetch tile 0 (rows s+rg+8k, k=0..3), clamped -> always in-bounds
    int n0 = s + rg;
    f4 nv0 = __builtin_nontemporal_load(&fp[min(n0,      emax) * 32 + c]);
    f4 nv1 = __builtin_nontemporal_load(&fp[min(n0 + 8,  emax) * 32 + c]);
    f4 nv2 = __builtin_nontemporal_load(&fp[min(n0 + 16, emax) * 32 + c]);
    f4 nv3 = __builtin_nontemporal_load(&fp[min(n0 + 24, emax) * 32 + c]);

    for (int t = 0; t < ntiles; ++t) {
        int r0 = s + t * 32 + rg;
        f4 c0 = nv0, c1 = nv1, c2 = nv2, c3 = nv3;

        // prefetch next tile: unconditional clamped loads (no divergence)
        int p0 = r0 + 32;
        nv0 = __builtin_nontemporal_load(&fp[min(p0,      emax) * 32 + c]);
        nv1 = __builtin_nontemporal_load(&fp[min(p0 + 8,  emax) * 32 + c]);
        nv2 = __builtin_nontemporal_load(&fp[min(p0 + 16, emax) * 32 + c]);
        nv3 = __builtin_nontemporal_load(&fp[min(p0 + 24, emax) * 32 + c]);

        // gate dots for this thread's 4 rows; butterfly across the 32-lane group
        float d0 = c0.x*w4.x + c0.y*w4.y + c0.z*w4.z + c0.w*w4.w;
        float d1 = c1.x*w4.x + c1.y*w4.y + c1.z*w4.z + c1.w*w4.w;
        float d2 = c2.x*w4.x + c2.y*w4.y + c2.z*w4.z + c2.w*w4.w;
        float d3 = c3.x*w4.x + c3.y*w4.y + c3.z*w4.z + c3.w*w4.w;
        #pragma unroll
        for (int off = 16; off; off >>= 1) {
            d0 += __shfl_xor(d0, off);
            d1 += __shfl_xor(d1, off);
            d2 += __shfl_xor(d2, off);
            d3 += __shfl_xor(d3, off);
        }
        // validity via per-lane selects only
        float g0 = (r0      < e) ? d0 + b0 : NEG;
        float g1 = (r0 + 8  < e) ? d1 + b0 : NEG;
        float g2 = (r0 + 16 < e) ? d2 + b0 : NEG;
        float g3 = (r0 + 24 < e) ? d3 + b0 : NEG;

        // group-private online softmax update (pure VALU)
        float m_new = fmaxf(m, fmaxf(fmaxf(g0, g1), fmaxf(g2, g3)));
        float scale = __expf(m - m_new);      // all-finite arguments
        float p0w = __expf(g0 - m_new);       // invalid row: exp(~-1e30) == 0 exactly,
        float p1w = __expf(g1 - m_new);       //  so clamped (real) data adds 0
        float p2w = __expf(g2 - m_new);
        float p3w = __expf(g3 - m_new);
        l = l * scale + (p0w + p1w) + (p2w + p3w);
        acc = acc * scale + p0w * c0 + p1w * c1 + p2w * c2 + p3w * c3;
        m = m_new;
        // never-valid group: m stays NEG, p == 1, acc accumulates real rows —
        // cancelled exactly at merge by weight exp(NEG - M) == 0.
    }

    // merge the 8 group states: M = max m_k; out = sum exp(m_k-M)*acc_k / sum exp(m_k-M)*l_k
    red[rg][c] = acc;
    if (c == 0) { mred[rg] = m; lred[rg] = l; }
    __syncthreads();
    if (rg == 0) {
        float M = mred[0];
        #pragma unroll
        for (int k = 1; k < 8; ++k) M = fmaxf(M, mred[k]);
        f4 r = {0.f, 0.f, 0.f, 0.f};
        float ltot = 0.0f;
        #pragma unroll
        for (int k = 0; k < 8; ++k) {
            float wgt = __expf(mred[k] - M);
            ltot += lred[k] * wgt;
            r += wgt * red[k][c];
        }
        float invl = 1.0f / ltot;            // len > 0: group with global max has wgt 1, l >= 1
        r *= invl;
        ((f4*)out)[g * 32 + c] = r;
    }
}

// ---------------- launch ----------------
extern "C" void kernel_launch(void* const* d_in, const int* in_sizes, int n_in,
                              void* d_out, int out_size, void* d_ws, size_t ws_size,
                              hipStream_t stream) {
    const float* feat = (const float*)d_in[0];
    const float* gw   = (const float*)d_in[1];
    const float* gb   = (const float*)d_in[2];
    const int*   seg  = (const int*)d_in[3];
    int N = in_sizes[0] / DD;                        // 500000

    fused_kernel<<<NSEG, 256, 0, stream>>>(feat, gw, gb, seg, N, (float*)d_out);
}